// Round 7
// baseline (165.070 us; speedup 1.0000x reference)
//
#include <hip/hip_runtime.h>
#include <math.h>

// Problem constants (fixed by setup_inputs)
#define W_ 192
#define H_ 192
#define D_ 160
#define B_ 2
#define HW_ (H_ * W_)

#define TX 32             // output tile x
#define TY 8              // output tile y
#define HY 12             // halo rows (TY + 4)
#define RAWP 41           // raw row stride, 40 data cols + odd stride (<=2-way banks)
#define RSP  33           // rowsum row stride, 32 data cols + odd stride (<=2-way banks)
#define CHUNK 32          // z-planes of output per block (5 chunks cover D=160)
#define PLANES (CHUNK + 4)
#define NZC 5             // z-chunks per batch
#define GX 6              // 192/32
#define GY 24             // 192/8
#define GZ (NZC * B_)     // 10
#define NBLK (GX * GY * GZ)   // 1440  <= 1536 resident capacity: ONE round
#define NTOT 11796480.0f      // 2*1*160*192*192

__global__ __launch_bounds__(256) void lncc_main(const float* __restrict__ src,
                                                 const float* __restrict__ tgt,
                                                 float* __restrict__ partial) {
    // SoA float LDS, double-buffered for the 1-barrier/plane pipeline.
    // Total 23728 B -> 6 blocks/CU resident; 1440 blocks -> all co-resident.
    __shared__ float rawS[2][HY][RAWP];
    __shared__ float rawT[2][HY][RAWP];
    __shared__ float rsS [2][HY][RSP];
    __shared__ float rsT [2][HY][RSP];
    __shared__ float rsS2[2][HY][RSP];
    __shared__ float rsT2[2][HY][RSP];
    __shared__ float rsST[2][HY][RSP];
    __shared__ float wsum[4];

    const int tid = threadIdx.x;
    const int bz  = blockIdx.z;
    const int b   = bz / NZC;                // batch 0..1
    const int z0  = (bz - b * NZC) * CHUNK;  // 0,32,64,96,128
    const int bx0 = blockIdx.x * TX - 4;     // raw col 0 <-> gx = bx0 (16B-aligned)
    const int by0 = blockIdx.y * TY - 2;

    // ---- staging decode: tid<120 loads one aligned float4 per array ----
    const int  sr  = tid / 10;               // row 0..11
    const int  sc4 = tid - sr * 10;          // float4 col 0..9
    const int  sc  = sc4 * 4;                // word col 0,4,..,36
    const int  sgx = bx0 + sc;               // multiple of 4 -> float4 aligned
    const int  sgy = by0 + sr;
    const bool sW  = (tid < 120);
    const bool sOk = sW && ((unsigned)sgx < (unsigned)W_) && ((unsigned)sgy < (unsigned)H_);
    const size_t sOff = (size_t)sgy * W_ + (size_t)sgx;   // valid only when sOk

    // ---- phase1 decode: 16 x-pairs x 12 rows = 192 threads, one rep ----
    const int  p0y = tid >> 4;               // row (only tid<192 active)
    const int  xp  = tid & 15;
    const bool pAct = (tid < 192);
    const int  rc  = 2 * xp + 2;             // raw read col base (window of out 2*xp)
    const int  wc  = 2 * xp;                 // rs write col base

    // ---- phase2 decode: thread owns output row y0, column tx ----
    const int tx = tid & 31;                 // 0..31
    const int y0 = tid >> 5;                 // 0..7

    // z-ring: NAMED scalars only (arrays -> scratch: round-4 disaster, rule #20).
    float q0s=0,q0t=0,q0a=0,q0b=0,q0c=0;
    float q1s=0,q1t=0,q1a=0,q1b=0,q1c=0;
    float q2s=0,q2t=0,q2a=0,q2b=0,q2c=0;
    float q3s=0,q3t=0,q3a=0,q3b=0,q3c=0;
    float q4s=0,q4t=0,q4a=0,q4b=0,q4c=0;
    float zS=0,zT=0,zA=0,zB=0,zC=0;
    float lsum = 0.0f;

    // phase2: y-sum of rowsums for plane j (buffer rbuf) + z-window + LNCC
    auto phase2 = [&](int rbuf, int j) {
        float yS,yT,yA,yB,yC;
        {
            const float* p = &rsS[rbuf][y0][tx];
            yS = p[0] + p[RSP] + p[2*RSP] + p[3*RSP] + p[4*RSP];
        }
        {
            const float* p = &rsT[rbuf][y0][tx];
            yT = p[0] + p[RSP] + p[2*RSP] + p[3*RSP] + p[4*RSP];
        }
        {
            const float* p = &rsS2[rbuf][y0][tx];
            yA = p[0] + p[RSP] + p[2*RSP] + p[3*RSP] + p[4*RSP];
        }
        {
            const float* p = &rsT2[rbuf][y0][tx];
            yB = p[0] + p[RSP] + p[2*RSP] + p[3*RSP] + p[4*RSP];
        }
        {
            const float* p = &rsST[rbuf][y0][tx];
            yC = p[0] + p[RSP] + p[2*RSP] + p[3*RSP] + p[4*RSP];
        }
        zS += yS - q0s;  zT += yT - q0t;  zA += yA - q0a;
        zB += yB - q0b;  zC += yC - q0c;
        q0s=q1s; q0t=q1t; q0a=q1a; q0b=q1b; q0c=q1c;
        q1s=q2s; q1t=q2t; q1a=q2a; q1b=q2b; q1c=q2c;
        q2s=q3s; q2t=q3t; q2a=q3a; q2b=q3b; q2c=q3c;
        q3s=q4s; q3t=q4t; q3a=q4a; q3b=q4b; q3c=q4c;
        q4s=yS;  q4t=yT;  q4a=yA;  q4b=yB;  q4c=yC;
        if (j >= 4) {
            const float inv = 1.0f / 125.0f;
            float ms = zS * inv, mt = zT * inv;
            float vs = fmaf(-ms, ms, zA * inv);
            float vt = fmaf(-mt, mt, zB * inv);
            float cr = fmaf(-ms, mt, zC * inv);
            float den = fmaf(vs, vt, 1e-5f);
            lsum = fmaf(cr * cr, __builtin_amdgcn_rcpf(den), lsum);
        }
    };

    // phase1: sliding x-window, 6 raw words -> 2 rowsums per array
    auto rowsum = [&](int buf, int row) {
        const float* pS = &rawS[buf][row][rc];
        const float* pT = &rawT[buf][row][rc];
        float v0=pS[0],v1=pS[1],v2=pS[2],v3=pS[3],v4=pS[4],v5=pS[5];
        float u0=pT[0],u1=pT[1],u2=pT[2],u3=pT[3],u4=pT[4],u5=pT[5];
        float m  = v1 + v2 + v3 + v4;
        float n  = u1 + u2 + u3 + u4;
        float qS = fmaf(v1,v1, fmaf(v2,v2, fmaf(v3,v3, v4*v4)));
        float qT = fmaf(u1,u1, fmaf(u2,u2, fmaf(u3,u3, u4*u4)));
        float qX = fmaf(v1,u1, fmaf(v2,u2, fmaf(v3,u3, v4*u4)));
        rsS [buf][row][wc]   = v0 + m;
        rsS [buf][row][wc+1] = m + v5;
        rsT [buf][row][wc]   = u0 + n;
        rsT [buf][row][wc+1] = n + u5;
        rsS2[buf][row][wc]   = fmaf(v0,v0,qS);
        rsS2[buf][row][wc+1] = fmaf(v5,v5,qS);
        rsT2[buf][row][wc]   = fmaf(u0,u0,qT);
        rsT2[buf][row][wc+1] = fmaf(u5,u5,qT);
        rsST[buf][row][wc]   = fmaf(v0,u0,qX);
        rsST[buf][row][wc+1] = fmaf(v5,u5,qX);
    };

    // ---- prologue: stage plane zp = z0-2 into raw[0] ----
    {
        float4 vS = make_float4(0,0,0,0), vT = make_float4(0,0,0,0);
        const int zp = z0 - 2;
        if (zp >= 0 && sOk) {
            const size_t base = (size_t)(b * D_ + zp) * (size_t)HW_;
            vS = *(const float4*)(src + base + sOff);
            vT = *(const float4*)(tgt + base + sOff);
        }
        if (sW) {
            rawS[0][sr][sc]=vS.x; rawS[0][sr][sc+1]=vS.y; rawS[0][sr][sc+2]=vS.z; rawS[0][sr][sc+3]=vS.w;
            rawT[0][sr][sc]=vT.x; rawT[0][sr][sc+1]=vT.y; rawT[0][sr][sc+2]=vT.z; rawT[0][sr][sc+3]=vT.w;
        }
    }

    for (int i = 0; i < PLANES; ++i) {
        const int buf = i & 1;
        __syncthreads();   // the ONLY barrier per plane
        // -- issue global loads for plane i+1 (consumed at loop end) --
        float4 vS = make_float4(0,0,0,0), vT = make_float4(0,0,0,0);
        const bool haveNext = (i + 1 < PLANES);
        const int  zpn = z0 - 1 + i;
        if (haveNext && zpn >= 0 && zpn < D_ && sOk) {
            const size_t base = (size_t)(b * D_ + zpn) * (size_t)HW_;
            vS = *(const float4*)(src + base + sOff);
            vT = *(const float4*)(tgt + base + sOff);
        }
        // -- phase2 for plane i-1 (rowsums written last iteration) --
        if (i >= 1) phase2(buf ^ 1, i - 1);
        // -- phase1 for plane i: x-rowsums raw[buf] -> rs[buf] --
        if (pAct) rowsum(buf, p0y);
        // -- write staged plane i+1 into raw[buf^1] (vmcnt wait lands here) --
        if (haveNext && sW) {
            rawS[buf^1][sr][sc]=vS.x; rawS[buf^1][sr][sc+1]=vS.y; rawS[buf^1][sr][sc+2]=vS.z; rawS[buf^1][sr][sc+3]=vS.w;
            rawT[buf^1][sr][sc]=vT.x; rawT[buf^1][sr][sc+1]=vT.y; rawT[buf^1][sr][sc+2]=vT.z; rawT[buf^1][sr][sc+3]=vT.w;
        }
    }
    __syncthreads();
    phase2((PLANES - 1) & 1, PLANES - 1);   // drain the pipeline

    // block reduction -> per-block partial (no atomics, no zero-kernel)
    #pragma unroll
    for (int off = 32; off > 0; off >>= 1)
        lsum += __shfl_down(lsum, off, 64);
    if ((tid & 63) == 0) wsum[tid >> 6] = lsum;
    __syncthreads();
    if (tid == 0) {
        const int bid = (blockIdx.z * GY + blockIdx.y) * GX + blockIdx.x;
        partial[bid] = wsum[0] + wsum[1] + wsum[2] + wsum[3];
    }
}

__global__ __launch_bounds__(256) void lncc_finalize(const float* __restrict__ partial,
                                                     float* __restrict__ out) {
    __shared__ float ws[4];
    const int t = threadIdx.x;
    float s = 0.0f;
    for (int i = t; i < NBLK; i += 256) s += partial[i];
    #pragma unroll
    for (int off = 32; off > 0; off >>= 1) s += __shfl_down(s, off, 64);
    if ((t & 63) == 0) ws[t >> 6] = s;
    __syncthreads();
    if (t == 0) {
        float tot = ws[0] + ws[1] + ws[2] + ws[3];
        float loss = 1.0f - tot * (1.0f / NTOT);
        if (isnan(loss) || isinf(loss)) loss = 1.0f;
        *out = loss;
    }
}

extern "C" void kernel_launch(void* const* d_in, const int* in_sizes, int n_in,
                              void* d_out, int out_size, void* d_ws, size_t ws_size,
                              hipStream_t stream) {
    const float* src = (const float*)d_in[0];
    const float* tgt = (const float*)d_in[1];
    float* out = (float*)d_out;
    float* partial = (float*)d_ws;   // NBLK floats of scratch

    dim3 grid(GX, GY, GZ);           // 6 x 24 x 10 = 1440 blocks (one resident round)
    dim3 block(256, 1, 1);
    lncc_main<<<grid, block, 0, stream>>>(src, tgt, partial);
    lncc_finalize<<<dim3(1), dim3(256), 0, stream>>>(partial, out);
}

// Round 8
// 156.260 us; speedup vs baseline: 1.0564x; 1.0564x over previous
//
#include <hip/hip_runtime.h>
#include <math.h>

// Problem constants (fixed by setup_inputs)
#define W_ 192
#define H_ 192
#define D_ 160
#define B_ 2
#define HW_ (H_ * W_)

#define TX 32             // output tile x
#define TY 8              // output tile y
#define HY 12             // halo rows (TY + 4)
#define RAWP 41           // raw row stride, 40 data cols + odd stride (<=2-way banks)
#define RSP  33           // rowsum row stride, 32 data cols + odd stride (<=2-way banks)
#define CHUNK 20          // z-planes of output per block
#define PLANES (CHUNK + 4) // 24 (even -> clean 2-unrolled pipeline)
#define GX 6              // 192/32
#define GY 24             // 192/8
#define GZ 16             // 8 z-chunks * 2 batches
#define NBLK (GX * GY * GZ)   // 2304 (9 blocks/CU queued: proven-best stream count)
#define NTOT 11796480.0f      // 2*1*160*192*192

__global__ __launch_bounds__(256) void lncc_main(const float* __restrict__ src,
                                                 const float* __restrict__ tgt,
                                                 float* __restrict__ partial) {
    // SoA float LDS, double-buffered; 23728 B -> 6 blocks/CU resident.
    __shared__ float rawS[2][HY][RAWP];
    __shared__ float rawT[2][HY][RAWP];
    __shared__ float rsS [2][HY][RSP];
    __shared__ float rsT [2][HY][RSP];
    __shared__ float rsS2[2][HY][RSP];
    __shared__ float rsT2[2][HY][RSP];
    __shared__ float rsST[2][HY][RSP];
    __shared__ float wsum[4];

    const int tid = threadIdx.x;
    const int bz  = blockIdx.z;
    const int b   = bz >> 3;                 // 8 chunks per batch
    const int z0  = (bz & 7) * CHUNK;
    const int bx0 = blockIdx.x * TX - 4;     // raw col 0 <-> gx = bx0 (16B-aligned)
    const int by0 = blockIdx.y * TY - 2;

    // ---- staging decode: tid<120 loads one aligned float4 per array ----
    const int  sr  = tid / 10;               // row 0..11
    const int  sc4 = tid - sr * 10;          // float4 col 0..9
    const int  sc  = sc4 * 4;                // word col 0,4,..,36
    const int  sgx = bx0 + sc;               // multiple of 4 -> float4 aligned
    const int  sgy = by0 + sr;
    const bool sW  = (tid < 120);
    const bool sOk = sW && ((unsigned)sgx < (unsigned)W_) && ((unsigned)sgy < (unsigned)H_);
    const size_t sOff = (size_t)sgy * W_ + (size_t)sgx;   // valid only when sOk

    // ---- phase1 decode: 16 x-pairs x 12 rows = 192 threads, one rep ----
    const int  p0y = tid >> 4;               // row (only tid<192 active)
    const int  xp  = tid & 15;
    const bool pAct = (tid < 192);
    const int  rc  = 2 * xp + 2;             // raw read col base (window of out 2*xp)
    const int  wc  = 2 * xp;                 // rs write col base

    // ---- phase2 decode: thread owns output row y0, column tx ----
    const int tx = tid & 31;                 // 0..31
    const int y0 = tid >> 5;                 // 0..7

    // z-ring: NAMED scalars only (arrays -> scratch: round-4 disaster, rule #20).
    float q0s=0,q0t=0,q0a=0,q0b=0,q0c=0;
    float q1s=0,q1t=0,q1a=0,q1b=0,q1c=0;
    float q2s=0,q2t=0,q2a=0,q2b=0,q2c=0;
    float q3s=0,q3t=0,q3a=0,q3b=0,q3c=0;
    float q4s=0,q4t=0,q4a=0,q4b=0,q4c=0;
    float zS=0,zT=0,zA=0,zB=0,zC=0;
    float lsum = 0.0f;

    // phase2: y-sum of rowsums for plane j (buffer rbuf) + z-window + LNCC
    auto phase2 = [&](int rbuf, int j) {
        float yS,yT,yA,yB,yC;
        {
            const float* p = &rsS[rbuf][y0][tx];
            yS = p[0] + p[RSP] + p[2*RSP] + p[3*RSP] + p[4*RSP];
        }
        {
            const float* p = &rsT[rbuf][y0][tx];
            yT = p[0] + p[RSP] + p[2*RSP] + p[3*RSP] + p[4*RSP];
        }
        {
            const float* p = &rsS2[rbuf][y0][tx];
            yA = p[0] + p[RSP] + p[2*RSP] + p[3*RSP] + p[4*RSP];
        }
        {
            const float* p = &rsT2[rbuf][y0][tx];
            yB = p[0] + p[RSP] + p[2*RSP] + p[3*RSP] + p[4*RSP];
        }
        {
            const float* p = &rsST[rbuf][y0][tx];
            yC = p[0] + p[RSP] + p[2*RSP] + p[3*RSP] + p[4*RSP];
        }
        zS += yS - q0s;  zT += yT - q0t;  zA += yA - q0a;
        zB += yB - q0b;  zC += yC - q0c;
        q0s=q1s; q0t=q1t; q0a=q1a; q0b=q1b; q0c=q1c;
        q1s=q2s; q1t=q2t; q1a=q2a; q1b=q2b; q1c=q2c;
        q2s=q3s; q2t=q3t; q2a=q3a; q2b=q3b; q2c=q3c;
        q3s=q4s; q3t=q4t; q3a=q4a; q3b=q4b; q3c=q4c;
        q4s=yS;  q4t=yT;  q4a=yA;  q4b=yB;  q4c=yC;
        if (j >= 4) {
            const float inv = 1.0f / 125.0f;
            float ms = zS * inv, mt = zT * inv;
            float vs = fmaf(-ms, ms, zA * inv);
            float vt = fmaf(-mt, mt, zB * inv);
            float cr = fmaf(-ms, mt, zC * inv);
            float den = fmaf(vs, vt, 1e-5f);
            lsum = fmaf(cr * cr, __builtin_amdgcn_rcpf(den), lsum);
        }
    };

    // phase1: sliding x-window, 6 raw words -> 2 rowsums per array
    auto rowsum = [&](int buf, int row) {
        const float* pS = &rawS[buf][row][rc];
        const float* pT = &rawT[buf][row][rc];
        float v0=pS[0],v1=pS[1],v2=pS[2],v3=pS[3],v4=pS[4],v5=pS[5];
        float u0=pT[0],u1=pT[1],u2=pT[2],u3=pT[3],u4=pT[4],u5=pT[5];
        float m  = v1 + v2 + v3 + v4;
        float n  = u1 + u2 + u3 + u4;
        float qS = fmaf(v1,v1, fmaf(v2,v2, fmaf(v3,v3, v4*v4)));
        float qT = fmaf(u1,u1, fmaf(u2,u2, fmaf(u3,u3, u4*u4)));
        float qX = fmaf(v1,u1, fmaf(v2,u2, fmaf(v3,u3, v4*u4)));
        rsS [buf][row][wc]   = v0 + m;
        rsS [buf][row][wc+1] = m + v5;
        rsT [buf][row][wc]   = u0 + n;
        rsT [buf][row][wc+1] = n + u5;
        rsS2[buf][row][wc]   = fmaf(v0,v0,qS);
        rsS2[buf][row][wc+1] = fmaf(v5,v5,qS);
        rsT2[buf][row][wc]   = fmaf(u0,u0,qT);
        rsT2[buf][row][wc+1] = fmaf(u5,u5,qT);
        rsST[buf][row][wc]   = fmaf(v0,u0,qX);
        rsST[buf][row][wc+1] = fmaf(v5,u5,qX);
    };

    // Depth-2 register prefetch pipeline:
    //   iter i: write LDS raw[i+1] from regs loaded at iter i-1;
    //           issue global load for plane i+2 into the other reg set.
    // Two named float4 sets (A,B) alternated by compile-time macro expansion.
    float4 aS, aT, bS, bT;

    // ---- prologue ----
    // Stage plane P0 (z = z0-2) directly into raw[0].
    {
        float4 vS = make_float4(0,0,0,0), vT = make_float4(0,0,0,0);
        const int zp = z0 - 2;
        if (zp >= 0 && sOk) {
            const size_t base = (size_t)(b * D_ + zp) * (size_t)HW_;
            vS = *(const float4*)(src + base + sOff);
            vT = *(const float4*)(tgt + base + sOff);
        }
        if (sW) {
            rawS[0][sr][sc]=vS.x; rawS[0][sr][sc+1]=vS.y; rawS[0][sr][sc+2]=vS.z; rawS[0][sr][sc+3]=vS.w;
            rawT[0][sr][sc]=vT.x; rawT[0][sr][sc+1]=vT.y; rawT[0][sr][sc+2]=vT.z; rawT[0][sr][sc+3]=vT.w;
        }
    }
    // Issue load of plane P1 (z = z0-1) into A (consumed by iter 0's LDS write).
    aS = make_float4(0,0,0,0);  aT = make_float4(0,0,0,0);
    {
        const int zl = z0 - 1;
        if (zl >= 0 && sOk) {
            const size_t base = (size_t)(b * D_ + zl) * (size_t)HW_;
            aS = *(const float4*)(src + base + sOff);
            aT = *(const float4*)(tgt + base + sOff);
        }
    }

    // One pipeline iteration. WS/WT: regs holding plane i+1 (written to LDS now).
    // LS/LT: regs receiving the load of plane i+2 (z = z0 + i), issued now.
    #define ITER(I, WS, WT, LS, LT) do {                                          \
        __syncthreads();   /* the ONLY barrier per plane */                       \
        LS = make_float4(0,0,0,0);  LT = make_float4(0,0,0,0);                    \
        {                                                                         \
            const int zl = z0 + (I);                                              \
            if ((I) + 2 < PLANES && zl < D_ && sOk) {                             \
                const size_t base = (size_t)(b * D_ + zl) * (size_t)HW_;          \
                LS = *(const float4*)(src + base + sOff);                         \
                LT = *(const float4*)(tgt + base + sOff);                         \
            }                                                                     \
        }                                                                         \
        if ((I) >= 1) phase2(((I) & 1) ^ 1, (I) - 1);                             \
        if (pAct) rowsum((I) & 1, p0y);                                           \
        if ((I) + 1 < PLANES && sW) {                                             \
            const int bw = ((I) & 1) ^ 1;                                         \
            rawS[bw][sr][sc]=WS.x; rawS[bw][sr][sc+1]=WS.y;                       \
            rawS[bw][sr][sc+2]=WS.z; rawS[bw][sr][sc+3]=WS.w;                     \
            rawT[bw][sr][sc]=WT.x; rawT[bw][sr][sc+1]=WT.y;                       \
            rawT[bw][sr][sc+2]=WT.z; rawT[bw][sr][sc+3]=WT.w;                     \
        }                                                                         \
    } while (0)

    for (int ip = 0; ip < PLANES; ip += 2) {
        ITER(ip,     aS, aT, bS, bT);   // even: write A (P ip+1), load into B (P ip+2)
        ITER(ip + 1, bS, bT, aS, aT);   // odd:  write B,          load into A
    }
    #undef ITER

    __syncthreads();
    phase2((PLANES - 1) & 1, PLANES - 1);   // drain the pipeline

    // block reduction -> per-block partial (no atomics, no zero-kernel)
    #pragma unroll
    for (int off = 32; off > 0; off >>= 1)
        lsum += __shfl_down(lsum, off, 64);
    if ((tid & 63) == 0) wsum[tid >> 6] = lsum;
    __syncthreads();
    if (tid == 0) {
        const int bid = (blockIdx.z * GY + blockIdx.y) * GX + blockIdx.x;
        partial[bid] = wsum[0] + wsum[1] + wsum[2] + wsum[3];
    }
}

__global__ __launch_bounds__(256) void lncc_finalize(const float* __restrict__ partial,
                                                     float* __restrict__ out) {
    __shared__ float ws[4];
    const int t = threadIdx.x;
    float s = 0.0f;
    for (int i = t; i < NBLK; i += 256) s += partial[i];
    #pragma unroll
    for (int off = 32; off > 0; off >>= 1) s += __shfl_down(s, off, 64);
    if ((t & 63) == 0) ws[t >> 6] = s;
    __syncthreads();
    if (t == 0) {
        float tot = ws[0] + ws[1] + ws[2] + ws[3];
        float loss = 1.0f - tot * (1.0f / NTOT);
        if (isnan(loss) || isinf(loss)) loss = 1.0f;
        *out = loss;
    }
}

extern "C" void kernel_launch(void* const* d_in, const int* in_sizes, int n_in,
                              void* d_out, int out_size, void* d_ws, size_t ws_size,
                              hipStream_t stream) {
    const float* src = (const float*)d_in[0];
    const float* tgt = (const float*)d_in[1];
    float* out = (float*)d_out;
    float* partial = (float*)d_ws;   // NBLK floats of scratch

    dim3 grid(GX, GY, GZ);           // 6 x 24 x 16 = 2304 blocks
    dim3 block(256, 1, 1);
    lncc_main<<<grid, block, 0, stream>>>(src, tgt, partial);
    lncc_finalize<<<dim3(1), dim3(256), 0, stream>>>(partial, out);
}